// Round 2
// 754.170 us; speedup vs baseline: 1.0638x; 1.0638x over previous
//
#include <hip/hip_runtime.h>

// ---------------------------------------------------------------------------
// Compile-time Wigner-3j (real spherical-harmonic basis, e3nn convention).
// Exact replication of the reference pipeline:
//   su2_cg (Racah) -> Q basis change with (-i)^l phase -> Re -> / frob norm
// then folded with alpha = sqrt(2*l3+1).
// ---------------------------------------------------------------------------

#define CEXPR __host__ __device__ constexpr

struct Cplx { double re, im; };
CEXPR Cplx cmul(Cplx a, Cplx b){ return {a.re*b.re - a.im*b.im, a.re*b.im + a.im*b.re}; }
CEXPR Cplx cadd(Cplx a, Cplx b){ return {a.re+b.re, a.im+b.im}; }
CEXPR Cplx cconj(Cplx a){ return {a.re, -a.im}; }
CEXPR Cplx cscale(double s, Cplx a){ return {s*a.re, s*a.im}; }

CEXPR double cfact(int n){ double r = 1.0; for (int i = 2; i <= n; ++i) r *= (double)i; return r; }

CEXPR double csqrt_(double x){
  if (x <= 0.0) return 0.0;
  double g = x > 1.0 ? x : 1.0;
  for (int i = 0; i < 80; ++i) g = 0.5*(g + x/g);
  return g;
}

// max dims: l1<=2 (5), l2<=3 (7), l3<=5 (11)
struct CGT { double c[5][7][11]; };

CEXPR CGT su2_cg(int j1, int j2, int j3){
  CGT T{};
  for (int m1 = -j1; m1 <= j1; ++m1){
    for (int m2 = -j2; m2 <= j2; ++m2){
      int m3 = m1 + m2;
      if (m3 < -j3 || m3 > j3) continue;
      double pref = csqrt_((double)(2*j3+1) * cfact(j3+j1-j2) * cfact(j3-j1+j2)
                           * cfact(j1+j2-j3) / cfact(j1+j2+j3+1));
      pref *= csqrt_(cfact(j3+m3)*cfact(j3-m3)*cfact(j1-m1)*cfact(j1+m1)*cfact(j2-m2)*cfact(j2+m2));
      double s = 0.0;
      for (int k = 0; k <= j1+j2-j3; ++k){
        int d1 = j1+j2-j3-k, d2 = j1-m1-k, d3 = j2+m2-k, d4 = j3-j2+m1+k, d5 = j3-j1-m2+k;
        if (d1 < 0 || d2 < 0 || d3 < 0 || d4 < 0 || d5 < 0) continue;
        double denom = cfact(k)*cfact(d1)*cfact(d2)*cfact(d3)*cfact(d4)*cfact(d5);
        s += ((k & 1) ? -1.0 : 1.0) / denom;
      }
      T.c[j1+m1][j2+m2][j3+m3] = pref * s;
    }
  }
  return T;
}

struct QM { Cplx q[11][11]; };

CEXPR QM qmat(int l){
  QM Q{};
  const double is2 = csqrt_(0.5);
  for (int m = -l; m < 0; ++m){
    Q.q[l+m][l-m] = Cplx{is2, 0.0};     // col = l + |m|
    Q.q[l+m][l+m] = Cplx{0.0, -is2};    // col = l - |m|
  }
  Q.q[l][l] = Cplx{1.0, 0.0};
  for (int m = 1; m <= l; ++m){
    double sg = (m & 1) ? -1.0 : 1.0;
    Q.q[l+m][l+m] = Cplx{sg*is2, 0.0};
    Q.q[l+m][l-m] = Cplx{0.0, sg*is2};
  }
  Cplx ph{1.0, 0.0};
  for (int i = 0; i < (l & 3); ++i) ph = cmul(ph, Cplx{0.0, -1.0});  // (-i)^l
  for (int r = 0; r < 2*l+1; ++r)
    for (int c = 0; c < 2*l+1; ++c)
      Q.q[r][c] = cmul(ph, Q.q[r][c]);
  return Q;
}

struct W3T { double w[5][7][11]; };

// returns alpha * w3j  (alpha = sqrt(2*l3+1)), tiny-noise entries zeroed
CEXPR W3T w3j_tensor(int l1, int l2, int l3){
  CGT cg = su2_cg(l1, l2, l3);
  QM Q1 = qmat(l1);
  QM Q2 = qmat(l2);
  QM Q3 = qmat(l3);
  const int n1 = 2*l1+1, n2 = 2*l2+1, n3 = 2*l3+1;
  W3T R{};
  double nrm2 = 0.0;
  for (int j = 0; j < n1; ++j){
    for (int l = 0; l < n2; ++l){
      for (int n = 0; n < n3; ++n){
        Cplx s{0.0, 0.0};
        for (int i = 0; i < n1; ++i){
          Cplx q1 = Q1.q[i][j];
          if (q1.re == 0.0 && q1.im == 0.0) continue;
          for (int k = 0; k < n2; ++k){
            Cplx q2 = Q2.q[k][l];
            if (q2.re == 0.0 && q2.im == 0.0) continue;
            int m = (i - l1) + (k - l2) + l3;          // m3 index (m1+m2=m3)
            if (m < 0 || m >= n3) continue;
            double cgv = cg.c[i][k][m];
            if (cgv == 0.0) continue;
            Cplx q3 = cconj(Q3.q[n][m]);
            if (q3.re == 0.0 && q3.im == 0.0) continue;
            s = cadd(s, cscale(cgv, cmul(cmul(q1, q2), q3)));
          }
        }
        R.w[j][l][n] = s.re;
        nrm2 += s.re * s.re;
      }
    }
  }
  double scale = csqrt_((double)(2*l3+1)) / csqrt_(nrm2);
  for (int j = 0; j < n1; ++j)
    for (int l = 0; l < n2; ++l)
      for (int n = 0; n < n3; ++n){
        double v = R.w[j][l][n] * scale;
        R.w[j][l][n] = (v > 1e-10 || v < -1e-10) ? v : 0.0;
      }
  return R;
}

// ---------------------------------------------------------------------------
// Device kernel
// ---------------------------------------------------------------------------

typedef float fv2  __attribute__((ext_vector_type(2), aligned(4)));
typedef float fv4  __attribute__((ext_vector_type(4), aligned(4)));
typedef float fv4a __attribute__((ext_vector_type(4), aligned(16)));

// Intra-wave LDS fence: each wave owns its staging buffer, so s_waitcnt
// lgkmcnt(0) (LDS pipe is in-order per wave) + a full scheduling barrier is
// sufficient ordering — no s_barrier, and critically NO vmcnt(0) drain, so
// global stores stay fire-and-forget across batches/rows.
__device__ __forceinline__ void lds_fence(){
  asm volatile("s_waitcnt lgkmcnt(0)" ::: "memory");
  __builtin_amdgcn_sched_barrier(0);
}

// Compute one path and stage its [64][N3] segment into the wave's LDS buffer.
// Lane-strided LDS writes (odd dword stride) are only 2-way bank-aliased = free.
template<int L1, int L2, int L3>
__device__ __forceinline__ void path_stage(const float* xv, const float* yv,
                                           float* __restrict__ seg, int u){
  static constexpr W3T W = w3j_tensor(L1, L2, L3);
  constexpr int N1 = 2*L1+1, N2 = 2*L2+1, N3 = 2*L3+1;
  #pragma unroll
  for (int k = 0; k < N3; ++k){
    float acc = 0.0f;
    #pragma unroll
    for (int i = 0; i < N1; ++i){
      #pragma unroll
      for (int j = 0; j < N2; ++j){
        const float c = (float)W.w[i][j][k];   // folds to an immediate after unroll
        if (c != 0.0f) acc = fmaf(c, xv[i]*yv[j], acc);
      }
    }
    seg[u*N3 + k] = acc;
  }
}

// Dense flush: segment is 64*N3 contiguous floats; lane i moves floats
// [4i,4i+4) of each 256-float chunk => every global_store_dwordx4 covers full
// contiguous 64B lines (one transaction per line, no partial-line writes).
template<int N3>
__device__ __forceinline__ void path_flush(const float* __restrict__ seg,
                                           float* __restrict__ gout, int u){
  constexpr int NCH = (N3 + 3) / 4;
  #pragma unroll
  for (int c = 0; c < NCH; ++c){
    const int idx = c*256 + 4*u;
    if ((c + 1) * 4 <= N3 /*compile-time: full chunk*/ || u < 16 * (N3 - 4*c)){
      fv4a v = *(const fv4a*)(seg + idx);      // ds_read_b128, conflict-free
      *(fv4a*)(gout + idx) = v;                // global_store_dwordx4, dense
    }
  }
}

// N3==1 paths are already dense (dword per lane, contiguous) — store direct.
template<int L1, int L2>
__device__ __forceinline__ void path_direct0(const float* xv, const float* yv,
                                             float* __restrict__ op, int u){
  static constexpr W3T W = w3j_tensor(L1, L2, 0);
  constexpr int N1 = 2*L1+1, N2 = 2*L2+1;
  float acc = 0.0f;
  #pragma unroll
  for (int i = 0; i < N1; ++i){
    #pragma unroll
    for (int j = 0; j < N2; ++j){
      const float c = (float)W.w[i][j][0];
      if (c != 0.0f) acc = fmaf(c, xv[i]*yv[j], acc);
    }
  }
  op[u] = acc;
}

// Per-wave staging: max batch is 39 dwords/lane -> 39*64*4 = 9984 B/wave,
// 39936 B/block -> 4 blocks/CU (16 waves/CU) by LDS.
#define BATCH_CAP 39

__global__ __launch_bounds__(256) void tp_kernel(const float* __restrict__ x,
                                                 const float* __restrict__ y,
                                                 float* __restrict__ out,
                                                 int rows)
{
  __shared__ __align__(16) float lds[4][BATCH_CAP * 64];

  const int u   = threadIdx.x & 63;                    // multiplicity index, lane = u
  const int w   = threadIdx.x >> 6;
  const int row = blockIdx.x * 4 + w;                  // 4 batch rows per block
  if (row >= rows) return;                             // no block-wide sync used -> safe

  float* wb = lds[w];

  const float* xr = x + (size_t)row * 576;
  const float* yr = y + (size_t)row * 16;

  // x fragments:  l=0 @ [0,64), l=1 @ [64,256) as [u][3], l=2 @ [256,576) as [u][5]
  float x0[1], x1[3], x2[5];
  x0[0] = xr[u];
  { fv2 t = *(const fv2*)(xr + 64 + 3*u);  x1[0] = t.x; x1[1] = t.y; x1[2] = xr[64 + 3*u + 2]; }
  { fv4 t = *(const fv4*)(xr + 256 + 5*u); x2[0] = t.x; x2[1] = t.y; x2[2] = t.z; x2[3] = t.w;
    x2[4] = xr[256 + 5*u + 4]; }

  // y: 16 floats, shared across the wave (same row) — broadcast loads
  float yv[16];
  #pragma unroll
  for (int q = 0; q < 4; ++q){
    fv4 t = *(const fv4*)(yr + 4*q);
    yv[4*q] = t.x; yv[4*q+1] = t.y; yv[4*q+2] = t.z; yv[4*q+3] = t.w;
  }
  const float* y0 = yv;      // l2=0
  const float* y1 = yv + 1;  // l2=1
  const float* y2 = yv + 4;  // l2=2
  const float* y3 = yv + 9;  // l2=3

  float* o = out + (size_t)row * 9216;

  // ---- dense N3==1 paths (direct dword stores, already full-line) ----------
  path_direct0<0,0>(x0, y0, o + 0,   u);
  path_direct0<1,1>(x1, y1, o + 64,  u);
  path_direct0<2,2>(x2, y2, o + 128, u);

  // ---- batch 1 (sum N3 = 34) ----------------------------------------------
  path_stage<0,1,1>(x0, y1, wb +  0*64, u);
  path_stage<0,2,2>(x0, y2, wb +  3*64, u);
  path_stage<0,3,3>(x0, y3, wb +  8*64, u);
  path_stage<1,0,1>(x1, y0, wb + 15*64, u);
  path_stage<1,1,1>(x1, y1, wb + 18*64, u);
  path_stage<1,1,2>(x1, y1, wb + 21*64, u);
  path_stage<1,2,1>(x1, y2, wb + 26*64, u);
  path_stage<1,2,2>(x1, y2, wb + 29*64, u);
  lds_fence();
  path_flush<3>(wb +  0*64, o + 192,  u);
  path_flush<5>(wb +  3*64, o + 1536, u);
  path_flush<7>(wb +  8*64, o + 4096, u);
  path_flush<3>(wb + 15*64, o + 384,  u);
  path_flush<3>(wb + 18*64, o + 1152, u);
  path_flush<5>(wb + 21*64, o + 1856, u);
  path_flush<3>(wb + 26*64, o + 576,  u);
  path_flush<5>(wb + 29*64, o + 3136, u);
  lds_fence();  // WAR: next batch's LDS writes vs this batch's reads

  // ---- batch 2 (sum N3 = 36) ----------------------------------------------
  path_stage<1,2,3>(x1, y2, wb +  0*64, u);
  path_stage<1,3,2>(x1, y3, wb +  7*64, u);
  path_stage<1,3,3>(x1, y3, wb + 12*64, u);
  path_stage<1,3,4>(x1, y3, wb + 19*64, u);
  path_stage<2,0,2>(x2, y0, wb + 28*64, u);
  path_stage<2,1,1>(x2, y1, wb + 33*64, u);
  lds_fence();
  path_flush<7>(wb +  0*64, o + 4544, u);
  path_flush<5>(wb +  7*64, o + 2176, u);
  path_flush<7>(wb + 12*64, o + 5888, u);
  path_flush<9>(wb + 19*64, o + 6784, u);
  path_flush<5>(wb + 28*64, o + 2496, u);
  path_flush<3>(wb + 33*64, o + 768,  u);
  lds_fence();

  // ---- batch 3 (sum N3 = 39) ----------------------------------------------
  path_stage<2,1,2>(x2, y1, wb +  0*64, u);
  path_stage<2,1,3>(x2, y1, wb +  5*64, u);
  path_stage<2,2,1>(x2, y2, wb + 12*64, u);
  path_stage<2,2,2>(x2, y2, wb + 15*64, u);
  path_stage<2,2,3>(x2, y2, wb + 20*64, u);
  path_stage<2,2,4>(x2, y2, wb + 27*64, u);
  path_stage<2,3,1>(x2, y3, wb + 36*64, u);
  lds_fence();
  path_flush<5>(wb +  0*64, o + 3456, u);
  path_flush<7>(wb +  5*64, o + 4992, u);
  path_flush<3>(wb + 12*64, o + 1344, u);
  path_flush<5>(wb + 15*64, o + 2816, u);
  path_flush<7>(wb + 20*64, o + 6336, u);
  path_flush<9>(wb + 27*64, o + 7360, u);
  path_flush<3>(wb + 36*64, o + 960,  u);
  lds_fence();

  // ---- batch 4 (sum N3 = 32) ----------------------------------------------
  path_stage<2,3,2>(x2, y3, wb +  0*64, u);
  path_stage<2,3,3>(x2, y3, wb +  5*64, u);
  path_stage<2,3,4>(x2, y3, wb + 12*64, u);
  path_stage<2,3,5>(x2, y3, wb + 21*64, u);
  lds_fence();
  path_flush<5> (wb +  0*64, o + 3776, u);
  path_flush<7> (wb +  5*64, o + 5440, u);
  path_flush<9> (wb + 12*64, o + 7936, u);
  path_flush<11>(wb + 21*64, o + 8512, u);
}

extern "C" void kernel_launch(void* const* d_in, const int* in_sizes, int n_in,
                              void* d_out, int out_size, void* d_ws, size_t ws_size,
                              hipStream_t stream)
{
  const float* x = (const float*)d_in[0];
  const float* y = (const float*)d_in[1];
  float* out = (float*)d_out;
  const int rows = in_sizes[0] / 576;   // 20000
  const int blocks = (rows + 3) / 4;    // 4 rows per 256-thread block
  hipLaunchKernelGGL(tp_kernel, dim3(blocks), dim3(256), 0, stream, x, y, out, rows);
}